// Round 8
// baseline (661.873 us; speedup 1.0000x reference)
//
#include <hip/hip_runtime.h>

constexpr int BB = 4, NN = 8192, KNB = 20;
constexpr int BN_ = BB * NN; // 32768
constexpr float EPSV = 1e-5f;

// ---------------- workspace layout (float offsets) ----------------
constexpr size_t OFF_MODE  = 0;                     // int mode
constexpr size_t OFF_PCNT  = 16;                    // int[4]
constexpr size_t OFF_PL    = 64;                    // float4[4][8192] = 131072 floats
constexpr size_t OFF_M0 = OFF_PL + 131072;          // zero region start
constexpr size_t OFF_S0 = OFF_M0 + 12;
constexpr size_t OFF_M1 = OFF_S0 + 144;
constexpr size_t OFF_S1 = OFF_M1 + 64;
constexpr size_t OFF_M2 = OFF_S1 + 64 * 64;
constexpr size_t OFF_S2 = OFF_M2 + 64;
constexpr size_t OFF_M3 = OFF_S2 + 64 * 64;
constexpr size_t OFF_S3 = OFF_M3 + 64;
constexpr size_t OFF_M4 = OFF_S3 + 64 * 64;
constexpr size_t OFF_S4 = OFF_M4 + 128;
constexpr size_t OFF_POOL = OFF_S4 + 128 * 128;
constexpr size_t OFF_ZEND = OFF_POOL + BB * 1024;   // zero region end
constexpr size_t OFF_A1 = OFF_ZEND;
constexpr size_t OFF_B1 = OFF_A1 + 64;
constexpr size_t OFF_A2 = OFF_B1 + 64;
constexpr size_t OFF_B2 = OFF_A2 + 64;
constexpr size_t OFF_A3 = OFF_B2 + 64;
constexpr size_t OFF_B3 = OFF_A3 + 64;
constexpr size_t OFF_A4 = OFF_B3 + 64;
constexpr size_t OFF_B4 = OFF_A4 + 128;
constexpr size_t OFF_A5 = OFF_B4 + 128;
constexpr size_t OFF_B5 = OFF_A5 + 1024;
constexpr size_t OFF_SH = OFF_B5 + 1024;            // 4*512
constexpr size_t OFF_WT1 = OFF_SH + BB * 512;       // [12][64]
constexpr size_t OFF_WT2 = OFF_WT1 + 768;           // [64][64]
constexpr size_t OFF_WT3 = OFF_WT2 + 4096;          // [64][64]
constexpr size_t OFF_WT4 = OFF_WT3 + 4096;          // [64][128]
constexpr size_t OFF_WT5_RAW = OFF_WT4 + 8192;
constexpr size_t OFF_WT5 = (OFF_WT5_RAW + 63) & ~size_t(63);  // [128][1024]
constexpr size_t OFF_H0_RAW = OFF_WT5 + 1024 * 128;
constexpr size_t OFF_H0 = (OFF_H0_RAW + 63) & ~size_t(63);  // [4][12][8192]
constexpr size_t OFF_H1 = OFF_H0 + (size_t)BB * 12 * NN;    // [4][64][8192]
constexpr size_t OFF_H2 = OFF_H1 + (size_t)BB * 64 * NN;    // [4][64][8192]
constexpr size_t OFF_H3 = OFF_H1;                           // alias (h1 dead)
constexpr size_t OFF_H4 = OFF_H2 + (size_t)BB * 64 * NN;    // [4][128][8192]
constexpr size_t OFF_P64  = OFF_H4;
constexpr size_t OFF_P128 = OFF_H1;
constexpr size_t WS_FLOATS = OFF_H4 + (size_t)BB * 128 * NN;

__device__ inline float dist3(const float4 c, float x0, float x1, float x2) {
  const float d0 = c.x - x0, d1 = c.y - x1, d2 = c.z - x2;
  return __builtin_fmaf(d0, d0, __builtin_fmaf(d1, d1, d2 * d2));
}

// ---------------- prep: detect bool storage, compact local points ----------------
__global__ __launch_bounds__(256) void k_prep(const unsigned int* __restrict__ li32,
                                              int* __restrict__ mode,
                                              int* __restrict__ pcnt,
                                              float4* __restrict__ pl,
                                              const float* __restrict__ x) {
  const int b = blockIdx.x;
  const int t = threadIdx.x;
  const int lane = t & 63;
  const int w = t >> 6;
  __shared__ int s_wc[4];
  __shared__ int s_base;
  __shared__ int s_any;
  if (t == 0) { s_base = 0; s_any = 0; }
  __syncthreads();
  unsigned int any = 0;
  for (int i = t; i < 2048; i += 256) any |= (li32[b * 2048 + i] > 1u) ? 1u : 0u;
  if (any) atomicOr(&s_any, 1);
  __syncthreads();
  const int md = s_any;   // 1 => stored as bytes
  if (b == 0 && t == 0) *mode = md;
  const unsigned char* p8 = (const unsigned char*)li32;
  const float* __restrict__ xb = x + (size_t)b * 3 * NN;
  for (int j0 = 0; j0 < NN; j0 += 256) {
    const int m = j0 + t;
    const int f = md ? (p8[b * NN + m] != 0) : (li32[b * NN + m] != 0);
    const unsigned long long mask = __ballot(f);
    const int pos = __popcll(mask & ((1ull << lane) - 1ull));
    if (lane == 0) s_wc[w] = (int)__popcll(mask);
    __syncthreads();
    int off = s_base;
    for (int ww = 0; ww < w; ++ww) off += s_wc[ww];
    const int tot = s_wc[0] + s_wc[1] + s_wc[2] + s_wc[3];
    if (f) pl[(size_t)b * NN + off + pos] =
        make_float4(xb[m], xb[NN + m], xb[2 * NN + m], __int_as_float(m));
    __syncthreads();
    if (t == 0) s_base += tot;
    __syncthreads();
  }
  if (t == 0) pcnt[b] = s_base;
}

// ---------------- transpose all weights: wtX[c][o] ----------------
__global__ void k_wtall(const float* __restrict__ w1, const float* __restrict__ w2,
                        const float* __restrict__ w3, const float* __restrict__ w4,
                        const float* __restrict__ w5, float* __restrict__ wt1,
                        float* __restrict__ wt2, float* __restrict__ wt3,
                        float* __restrict__ wt4, float* __restrict__ wt5) {
  const int i = blockIdx.x * 256 + threadIdx.x;
  if (i < 768)        { const int o = i / 12,  c = i % 12;  wt1[c * 64 + o]  = w1[i]; }
  else if (i < 4864)  { const int j = i - 768;  const int o = j >> 6, c = j & 63;  wt2[c * 64 + o]  = w2[j]; }
  else if (i < 8960)  { const int j = i - 4864; const int o = j >> 6, c = j & 63;  wt3[c * 64 + o]  = w3[j]; }
  else if (i < 17152) { const int j = i - 8960; const int o = j >> 6, c = j & 63;  wt4[c * 128 + o] = w4[j]; }
  else if (i < 148224){ const int j = i - 17152;const int o = j >> 7, c = j & 127; wt5[c * 1024 + o] = w5[j]; }
}

// ---------------- kNN + covariance -> h0 [4][12][8192] ----------------
// 2048 blocks x 256 threads: 16 queries (qid=t&15) x 16 candidate partitions
// (part=t>>4). ~24KB LDS -> 6 blocks/CU; grid gives 8/CU -> 24 waves/CU.
__global__ __launch_bounds__(256) void k_knn(const float* __restrict__ x,
                                             const float4* __restrict__ pl,
                                             const int* __restrict__ pcnt,
                                             float* __restrict__ h0) {
  const int blk  = blockIdx.x;
  const int b    = blk >> 9;
  const int tile = blk & 511;
  const int t    = threadIdx.x;
  const int qid  = t & 15;
  const int part = t >> 4;              // 0..15
  const int n    = tile * 16 + qid;

  __shared__ float s_pool[256 * 21];    // lists [t][21]; first 8KB alias dbuf
  __shared__ float s_T[16];
  __shared__ float s_red[16][13];
  __shared__ int   s_tc[16];
  __shared__ int   s_ti[16][24];
  float* __restrict__ s_dbuf  = s_pool; // [8][256]
  int*   __restrict__ s_dbufi = (int*)s_pool;

  const float* __restrict__ xb  = x + (size_t)b * 3 * NN;
  const float4* __restrict__ plb = pl + (size_t)b * NN;
  const int cnt = pcnt[b];
  const float xn0 = xb[n], xn1 = xb[NN + n], xn2 = xb[2 * NN + n];

  const int jlo = (cnt * part) >> 4;
  const int jhi = (cnt * (part + 1)) >> 4;

  float tk[KNB];
#pragma unroll
  for (int i = 0; i < KNB; ++i) tk[i] = 3.0e38f;

  // ---- phase 1: buffered top-20 (distances only) ----
  {
    float thr = 3.0e38f;
    int bc = 0;
#pragma unroll 2
    for (int j = jlo; j < jhi; ++j) {
      const float4 c = plb[j];
      const float d = dist3(c, xn0, xn1, xn2);
      if (d < thr) { s_dbuf[bc * 256 + t] = d; ++bc; }
      if (__any(bc == 8)) {
        for (int i = 0; i < bc; ++i) {
          float dv = s_dbuf[i * 256 + t];
          if (dv < tk[KNB - 1]) {
#pragma unroll
            for (int q2 = 0; q2 < KNB; ++q2) {
              const float lo = fminf(tk[q2], dv);
              dv = fmaxf(tk[q2], dv);
              tk[q2] = lo;
            }
          }
        }
        bc = 0;
        thr = tk[KNB - 1];
      }
    }
    for (int i = 0; i < bc; ++i) {
      float dv = s_dbuf[i * 256 + t];
      if (dv < tk[KNB - 1]) {
#pragma unroll
        for (int q2 = 0; q2 < KNB; ++q2) {
          const float lo = fminf(tk[q2], dv);
          dv = fmaxf(tk[q2], dv);
          tk[q2] = lo;
        }
      }
    }
  }
  __syncthreads();   // dbuf dead; lists may overwrite

  {
    const int base = t * 21;
#pragma unroll
    for (int i = 0; i < KNB; ++i) s_pool[base + i] = tk[i];
    s_pool[base + KNB] = 3.0e38f;     // sentinel
  }
  __syncthreads();

  if (t < 16) {  // 16-way merge -> exact 20th smallest for query t
    int i0=0,i1=0,i2=0,i3=0,i4=0,i5=0,i6=0,i7=0;
    int i8=0,i9=0,i10=0,i11=0,i12=0,i13=0,i14=0,i15=0;
    float T = 0.f;
    for (int c = 0; c < KNB; ++c) {
      const float v0  = s_pool[( 0*16 + t)*21 + i0];
      const float v1  = s_pool[( 1*16 + t)*21 + i1];
      const float v2  = s_pool[( 2*16 + t)*21 + i2];
      const float v3  = s_pool[( 3*16 + t)*21 + i3];
      const float v4  = s_pool[( 4*16 + t)*21 + i4];
      const float v5  = s_pool[( 5*16 + t)*21 + i5];
      const float v6  = s_pool[( 6*16 + t)*21 + i6];
      const float v7  = s_pool[( 7*16 + t)*21 + i7];
      const float v8  = s_pool[( 8*16 + t)*21 + i8];
      const float v9  = s_pool[( 9*16 + t)*21 + i9];
      const float v10 = s_pool[(10*16 + t)*21 + i10];
      const float v11 = s_pool[(11*16 + t)*21 + i11];
      const float v12 = s_pool[(12*16 + t)*21 + i12];
      const float v13 = s_pool[(13*16 + t)*21 + i13];
      const float v14 = s_pool[(14*16 + t)*21 + i14];
      const float v15 = s_pool[(15*16 + t)*21 + i15];
      float best = fminf(fminf(fminf(fminf(v0,v1),fminf(v2,v3)),
                               fminf(fminf(v4,v5),fminf(v6,v7))),
                         fminf(fminf(fminf(v8,v9),fminf(v10,v11)),
                               fminf(fminf(v12,v13),fminf(v14,v15))));
      int adv, taken;
      adv = (v0  == best) ? 1 : 0;           i0  += adv; taken  = adv;
      adv = (!taken && v1  == best) ? 1 : 0; i1  += adv; taken |= adv;
      adv = (!taken && v2  == best) ? 1 : 0; i2  += adv; taken |= adv;
      adv = (!taken && v3  == best) ? 1 : 0; i3  += adv; taken |= adv;
      adv = (!taken && v4  == best) ? 1 : 0; i4  += adv; taken |= adv;
      adv = (!taken && v5  == best) ? 1 : 0; i5  += adv; taken |= adv;
      adv = (!taken && v6  == best) ? 1 : 0; i6  += adv; taken |= adv;
      adv = (!taken && v7  == best) ? 1 : 0; i7  += adv; taken |= adv;
      adv = (!taken && v8  == best) ? 1 : 0; i8  += adv; taken |= adv;
      adv = (!taken && v9  == best) ? 1 : 0; i9  += adv; taken |= adv;
      adv = (!taken && v10 == best) ? 1 : 0; i10 += adv; taken |= adv;
      adv = (!taken && v11 == best) ? 1 : 0; i11 += adv; taken |= adv;
      adv = (!taken && v12 == best) ? 1 : 0; i12 += adv; taken |= adv;
      adv = (!taken && v13 == best) ? 1 : 0; i13 += adv; taken |= adv;
      adv = (!taken && v14 == best) ? 1 : 0; i14 += adv; taken |= adv;
      adv = (!taken && v15 == best) ? 1 : 0; i15 += adv;
      T = best;
    }
    s_T[t] = T;
    s_tc[t] = 0;
  }
  __syncthreads();
  const float T = s_T[qid];

  // ---- phase 2: buffered hits (d <= T); moments + ties at flush ----
  float sx = 0, sy = 0, sz = 0;
  float xx = 0, xy = 0, xz = 0, yy = 0, yz = 0, zz = 0;
  float clf = 0;
  {
    s_dbufi[t] = jlo;   // seed slot 0 (valid index for masked lanes)
    int bc = 0;
    for (int j = jlo; j < jhi; ++j) {
      const float4 c = plb[j];
      const float d = dist3(c, xn0, xn1, xn2);
      if (d <= T) { s_dbufi[bc * 256 + t] = j; ++bc; }
      if (__any(bc == 8)) {
        int jj[8]; float4 cc[8];
#pragma unroll
        for (int i = 0; i < 8; ++i) {
          const int slot = (i < bc) ? i : 0;
          jj[i] = s_dbufi[slot * 256 + t];
          cc[i] = plb[jj[i]];
        }
#pragma unroll
        for (int i = 0; i < 8; ++i) {
          if (i < bc) {
            const float d2 = dist3(cc[i], xn0, xn1, xn2);
            if (d2 < T) {
              clf += 1.f;
              sx += cc[i].x; sy += cc[i].y; sz += cc[i].z;
              xx = __builtin_fmaf(cc[i].x, cc[i].x, xx);
              xy = __builtin_fmaf(cc[i].x, cc[i].y, xy);
              xz = __builtin_fmaf(cc[i].x, cc[i].z, xz);
              yy = __builtin_fmaf(cc[i].y, cc[i].y, yy);
              yz = __builtin_fmaf(cc[i].y, cc[i].z, yz);
              zz = __builtin_fmaf(cc[i].z, cc[i].z, zz);
            } else {
              const int pos = atomicAdd(&s_tc[qid], 1);
              if (pos < 24) s_ti[qid][pos] = jj[i];
            }
          }
        }
        bc = 0;
      }
    }
    if (bc > 0) {
      int jj[8]; float4 cc[8];
#pragma unroll
      for (int i = 0; i < 8; ++i) {
        const int slot = (i < bc) ? i : 0;
        jj[i] = s_dbufi[slot * 256 + t];
        cc[i] = plb[jj[i]];
      }
#pragma unroll
      for (int i = 0; i < 8; ++i) {
        if (i < bc) {
          const float d2 = dist3(cc[i], xn0, xn1, xn2);
          if (d2 < T) {
            clf += 1.f;
            sx += cc[i].x; sy += cc[i].y; sz += cc[i].z;
            xx = __builtin_fmaf(cc[i].x, cc[i].x, xx);
            xy = __builtin_fmaf(cc[i].x, cc[i].y, xy);
            xz = __builtin_fmaf(cc[i].x, cc[i].z, xz);
            yy = __builtin_fmaf(cc[i].y, cc[i].y, yy);
            yz = __builtin_fmaf(cc[i].y, cc[i].z, yz);
            zz = __builtin_fmaf(cc[i].z, cc[i].z, zz);
          } else {
            const int pos = atomicAdd(&s_tc[qid], 1);
            if (pos < 24) s_ti[qid][pos] = jj[i];
          }
        }
      }
    }
  }
  __syncthreads();   // phase-2 reads done before partials overwrite s_pool
  {
    const int base = t * 13;
    s_pool[base + 0] = sx; s_pool[base + 1] = sy; s_pool[base + 2] = sz;
    s_pool[base + 3] = xx; s_pool[base + 4] = xy; s_pool[base + 5] = xz;
    s_pool[base + 6] = yy; s_pool[base + 7] = yz; s_pool[base + 8] = zz;
    s_pool[base + 9] = clf;
  }
  __syncthreads();
  {
    const int q2 = t & 15, a = t >> 4;   // a in 0..15
    if (a < 13) {
      float s = 0.f;
#pragma unroll
      for (int p = 0; p < 16; ++p) s += s_pool[(p * 16 + q2) * 13 + a];
      s_red[q2][a] = s;
    }
  }
  __syncthreads();

  if (t < 16) {
    float fsx = s_red[t][0], fsy = s_red[t][1], fsz = s_red[t][2];
    float fxx = s_red[t][3], fxy = s_red[t][4], fxz = s_red[t][5];
    float fyy = s_red[t][6], fyz = s_red[t][7], fzz = s_red[t][8];
    const int cl = (int)s_red[t][9];
    const int r = KNB - cl;
    const int tc = min(s_tc[t], 24);
    int kk = cl;
    int prev = -1;
    for (int s = 0; s < r; ++s) {
      int best = 0x7fffffff;
      for (int u = 0; u < tc; ++u) {
        const int mi2 = s_ti[t][u];
        if (mi2 > prev && mi2 < best) best = mi2;
      }
      if (best == 0x7fffffff) break;
      const float4 pp = plb[best];
      fsx += pp.x; fsy += pp.y; fsz += pp.z;
      fxx = __builtin_fmaf(pp.x, pp.x, fxx);
      fxy = __builtin_fmaf(pp.x, pp.y, fxy);
      fxz = __builtin_fmaf(pp.x, pp.z, fxz);
      fyy = __builtin_fmaf(pp.y, pp.y, fyy);
      fyz = __builtin_fmaf(pp.y, pp.z, fyz);
      fzz = __builtin_fmaf(pp.z, pp.z, fzz);
      prev = best;
      ++kk;
    }
    const float kf = (float)max(kk, 1);
    const float inv = 1.0f / kf;
    const float mx = fsx * inv, my = fsy * inv, mz = fsz * inv;
    const float c00 = fxx - kf * mx * mx;
    const float c01 = fxy - kf * mx * my;
    const float c02 = fxz - kf * mx * mz;
    const float c11 = fyy - kf * my * my;
    const float c12 = fyz - kf * my * mz;
    const float c22 = fzz - kf * mz * mz;
    const float qx0 = xb[n], qx1 = xb[NN + n], qx2 = xb[2 * NN + n];
    float* __restrict__ op = h0 + (size_t)b * 12 * NN + n;
    op[0] = qx0; op[(size_t)NN] = qx1; op[(size_t)2 * NN] = qx2;
    op[(size_t)3 * NN] = c00; op[(size_t)4 * NN]  = c01; op[(size_t)5 * NN]  = c02;
    op[(size_t)6 * NN] = c01; op[(size_t)7 * NN]  = c11; op[(size_t)8 * NN]  = c12;
    op[(size_t)9 * NN] = c02; op[(size_t)10 * NN] = c12; op[(size_t)11 * NN] = c22;
  }
}

// ---------------- stats (small C) ----------------
template <int C>
__global__ __launch_bounds__(256) void k_stats_small(const float* __restrict__ h,
                                                     float* __restrict__ mo,
                                                     float* __restrict__ So) {
  constexpr int NP  = C * (C + 1) / 2;
  constexpr int KPT = (NP + 255) / 256;
  __shared__ float tile[C][65];
  const int t = threadIdx.x;
  float acc[KPT];
#pragma unroll
  for (int e = 0; e < KPT; ++e) acc[e] = 0.f;
  float accm = 0.f;
  for (int tl = blockIdx.x; tl < BN_ / 64; tl += gridDim.x) {
    const int b  = tl >> 7;
    const int p0 = (tl & 127) * 64;
    for (int idx = t; idx < C * 64; idx += 256) {
      const int c = idx >> 6, p = idx & 63;
      tile[c][p] = h[((size_t)b * C + c) * NN + p0 + p];
    }
    __syncthreads();
    {
      int ii = 0, rem = t;
#pragma unroll
      for (int e = 0; e < KPT; ++e) {
        const int lin = t + 256 * e;
        if (lin < NP) {
          while (rem >= C - ii) { rem -= C - ii; ++ii; }
          const int jj = ii + rem;
          float s = 0.f;
#pragma unroll 8
          for (int p = 0; p < 64; ++p) s = __builtin_fmaf(tile[ii][p], tile[jj][p], s);
          acc[e] += s;
        }
        rem += 256;
      }
    }
    if (t < C) {
      float s = 0.f;
#pragma unroll 8
      for (int p = 0; p < 64; ++p) s += tile[t][p];
      accm += s;
    }
    __syncthreads();
  }
  {
    int ii = 0, rem = t;
#pragma unroll
    for (int e = 0; e < KPT; ++e) {
      const int lin = t + 256 * e;
      if (lin < NP) {
        while (rem >= C - ii) { rem -= C - ii; ++ii; }
        atomicAdd(&So[ii * C + ii + rem], acc[e]);
      }
      rem += 256;
    }
  }
  if (t < C) atomicAdd(&mo[t], accm);
}

// ---------------- stats stage A (C=64/128): per-block partials ----------------
template <int C>
__global__ __launch_bounds__(512) void k_stats(const float* __restrict__ h,
                                               float* __restrict__ part) {
  constexpr int G      = (C == 128) ? 8 : 4;
  constexpr int NPB    = 136 * G * G;
  constexpr int ROWLEN = NPB + C;
  constexpr int STR    = C + 4;
  __shared__ float ht[128][STR];
  __shared__ float red[136][G * G];
  const int t   = threadIdx.x;
  const int blk = blockIdx.x;
  const int b   = blk >> 6;
  const int p0  = (blk & 63) * 128;
  for (int i = t; i < C * 128; i += 512) {
    const int c = i >> 7, p = i & 127;
    ht[p][c] = h[((size_t)b * C + c) * NN + p0 + p];
  }
  __syncthreads();
  const int s  = t >> 8;
  const int pb = t & 255;
  const int bi = pb & 15;
  const int bj = pb >> 4;
  const bool act = (bi <= bj);
  float acc[G * G];
#pragma unroll
  for (int g = 0; g < G * G; ++g) acc[g] = 0.f;
  if (act) {
    for (int p = s * 64; p < s * 64 + 64; ++p) {
      float a[G], bv[G];
      *(float4*)&a[0] = *(const float4*)&ht[p][bi * G];
      *(float4*)&bv[0] = *(const float4*)&ht[p][bj * G];
      if constexpr (G == 8) {
        *(float4*)&a[4] = *(const float4*)&ht[p][bi * G + 4];
        *(float4*)&bv[4] = *(const float4*)&ht[p][bj * G + 4];
      }
#pragma unroll
      for (int gi = 0; gi < G; ++gi)
#pragma unroll
        for (int gj = 0; gj < G; ++gj)
          acc[gi * G + gj] = __builtin_fmaf(a[gi], bv[gj], acc[gi * G + gj]);
    }
  }
  const int rank = bj * (bj + 1) / 2 + bi;
  if (s == 1 && act) {
#pragma unroll
    for (int g = 0; g < G * G; ++g) red[rank][g] = acc[g];
  }
  __syncthreads();
  float* __restrict__ prow = part + (size_t)blk * ROWLEN;
  if (s == 0 && act) {
#pragma unroll
    for (int g = 0; g < G * G; g += 4) {
      float4 v;
      v.x = acc[g + 0] + red[rank][g + 0];
      v.y = acc[g + 1] + red[rank][g + 1];
      v.z = acc[g + 2] + red[rank][g + 2];
      v.w = acc[g + 3] + red[rank][g + 3];
      *(float4*)&prow[rank * G * G + g] = v;
    }
  }
  if (t < C) {
    float sm = 0.f;
#pragma unroll 8
    for (int p = 0; p < 128; ++p) sm += ht[p][t];
    prow[NPB + t] = sm;
  }
}

// ---------------- stats stage B ----------------
template <int C>
__global__ __launch_bounds__(256) void k_sred(const float* __restrict__ part,
                                              float* __restrict__ mo,
                                              float* __restrict__ So) {
  constexpr int G      = (C == 128) ? 8 : 4;
  constexpr int GG     = G * G;
  constexpr int NPB    = 136 * GG;
  constexpr int ROWLEN = NPB + C;
  const int e = blockIdx.x * 256 + threadIdx.x;
  if (e >= ROWLEN) return;
  const float* __restrict__ p = part + e;
  float s = 0.f;
#pragma unroll 8
  for (int r = 0; r < 256; ++r) s += p[(size_t)r * ROWLEN];
  if (e < NPB) {
    const int rank = e / GG;
    const int g    = e - rank * GG;
    int bj = 0;
    while ((bj + 1) * (bj + 2) / 2 <= rank) ++bj;
    const int bi = rank - bj * (bj + 1) / 2;
    const int gi = g / G, gj = g - gi * G;
    So[(bi * G + gi) * C + (bj * G + gj)] = s;
  } else {
    mo[e - NPB] = s;
  }
}

// ---------------- solve BN affine ----------------
template <int CIN, int COUT>
__global__ __launch_bounds__(256) void k_solve(const float* __restrict__ w, const float* __restrict__ g,
                        const float* __restrict__ bb, const float* __restrict__ m,
                        const float* __restrict__ S, float* __restrict__ A,
                        float* __restrict__ Bc) {
  const int wv   = threadIdx.x >> 6;
  const int lane = threadIdx.x & 63;
  const int o    = blockIdx.x * 4 + wv;
  if (o >= COUT) return;
  const float* __restrict__ wr = w + (size_t)o * CIN;
  float mu = 0.f;
  for (int i = lane; i < CIN; i += 64) mu = __builtin_fmaf(wr[i], m[i], mu);
  float e2 = 0.f;
#pragma unroll 4
  for (int lin = lane; lin < CIN * CIN; lin += 64) {
    const int i = lin / CIN;
    const int j = lin - i * CIN;
    const int lo = min(i, j), hi = max(i, j);
    e2 = __builtin_fmaf(wr[i] * wr[j], S[lo * CIN + hi], e2);
  }
#pragma unroll
  for (int off = 32; off >= 1; off >>= 1) {
    mu += __shfl_xor(mu, off, 64);
    e2 += __shfl_xor(e2, off, 64);
  }
  if (lane == 0) {
    mu *= (1.0f / BN_);
    e2 *= (1.0f / BN_);
    const float var = e2 - mu * mu;
    const float a = g[o] / sqrtf(var + EPSV);
    A[o] = a;
    Bc[o] = bb[o] - mu * a;
  }
}

// ---------------- conv GEMM: 64o x 64p tile, thread 4o x 4p ----------------
template <int CIN, int COUT>
__global__ __launch_bounds__(256) void k_cgemm(const float* __restrict__ hin,
                                               const float* __restrict__ wt, // [CIN][COUT]
                                               const float* __restrict__ A,
                                               const float* __restrict__ Bc,
                                               float* __restrict__ outp) {
  constexpr int nOT = COUT / 64;
  __shared__ float tin[CIN][64];
  __shared__ float twt[CIN][64];
  const int blk = blockIdx.x;
  const int ot  = blk % nOT;
  const int pt  = blk / nOT;
  const int b   = pt >> 7;
  const int p0  = (pt & 127) * 64;
  const int o0  = ot * 64;
  const int t   = threadIdx.x;

  for (int i = t; i < CIN * 16; i += 256) {
    const int c = i >> 4, sgm = i & 15;
    *(float4*)&tin[c][sgm * 4] =
        *(const float4*)&hin[((size_t)b * CIN + c) * NN + p0 + sgm * 4];
    *(float4*)&twt[c][sgm * 4] =
        *(const float4*)&wt[(size_t)c * COUT + o0 + sgm * 4];
  }
  __syncthreads();

  const int to = t & 15;
  const int tp = t >> 4;
  float acc[4][4];
#pragma unroll
  for (int i = 0; i < 4; ++i)
#pragma unroll
    for (int j = 0; j < 4; ++j) acc[i][j] = 0.f;

#pragma unroll 4
  for (int c = 0; c < CIN; ++c) {
    const float4 av = *(const float4*)&twt[c][to * 4];
    const float4 pv = *(const float4*)&tin[c][tp * 4];
    const float aa[4] = {av.x, av.y, av.z, av.w};
    const float pp[4] = {pv.x, pv.y, pv.z, pv.w};
#pragma unroll
    for (int i = 0; i < 4; ++i)
#pragma unroll
      for (int j = 0; j < 4; ++j)
        acc[i][j] = __builtin_fmaf(aa[i], pp[j], acc[i][j]);
  }

#pragma unroll
  for (int i = 0; i < 4; ++i) {
    const int o = o0 + to * 4 + i;
    const float Ao = A[o], Bo = Bc[o];
    float4 vv;
    vv.x = fmaxf(__builtin_fmaf(acc[i][0], Ao, Bo), 0.f);
    vv.y = fmaxf(__builtin_fmaf(acc[i][1], Ao, Bo), 0.f);
    vv.z = fmaxf(__builtin_fmaf(acc[i][2], Ao, Bo), 0.f);
    vv.w = fmaxf(__builtin_fmaf(acc[i][3], Ao, Bo), 0.f);
    *(float4*)&outp[((size_t)b * COUT + o) * NN + p0 + tp * 4] = vv;
  }
}

// ---------------- conv5 + BN + ReLU + max-pool: 128o x 64p, K chunked ----------------
__global__ __launch_bounds__(256) void k_cgemm5(const float* __restrict__ h4,
                                                const float* __restrict__ wt, // [128][1024]
                                                const float* __restrict__ A,
                                                const float* __restrict__ Bc,
                                                float* __restrict__ pooled) {
  __shared__ float tin[64][64];    // 16 KB
  __shared__ float twt[64][128];   // 32 KB
  const int blk = blockIdx.x;      // 4096 = 8 otiles (fast) x 512 ptiles
  const int ot  = blk & 7;
  const int pt  = blk >> 3;
  const int b   = pt >> 7;
  const int p0  = (pt & 127) * 64;
  const int o0  = ot * 128;
  const int t   = threadIdx.x;
  const int to  = t & 15;          // o-subtile of 8
  const int tp  = t >> 4;          // p-subtile of 4

  float acc[8][4];
#pragma unroll
  for (int i = 0; i < 8; ++i)
#pragma unroll
    for (int j = 0; j < 4; ++j) acc[i][j] = 0.f;

  for (int kc = 0; kc < 128; kc += 64) {
    if (kc) __syncthreads();
    for (int i = t; i < 64 * 16; i += 256) {
      const int c = i >> 4, sg = i & 15;
      *(float4*)&tin[c][sg * 4] =
          *(const float4*)&h4[((size_t)b * 128 + kc + c) * NN + p0 + sg * 4];
    }
    for (int i = t; i < 64 * 32; i += 256) {
      const int c = i >> 5, sg = i & 31;
      *(float4*)&twt[c][sg * 4] =
          *(const float4*)&wt[(size_t)(kc + c) * 1024 + o0 + sg * 4];
    }
    __syncthreads();
#pragma unroll 2
    for (int c = 0; c < 64; ++c) {
      float w8[8], p4[4];
      *(float4*)&w8[0] = *(const float4*)&twt[c][to * 8];
      *(float4*)&w8[4] = *(const float4*)&twt[c][to * 8 + 4];
      *(float4*)&p4[0] = *(const float4*)&tin[c][tp * 4];
#pragma unroll
      for (int i = 0; i < 8; ++i)
#pragma unroll
        for (int j = 0; j < 4; ++j)
          acc[i][j] = __builtin_fmaf(w8[i], p4[j], acc[i][j]);
    }
  }

  float mx[8];
#pragma unroll
  for (int i = 0; i < 8; ++i) {
    const int o = o0 + to * 8 + i;
    const float a = A[o], bo = Bc[o];
    float v0 = fmaxf(__builtin_fmaf(acc[i][0], a, bo), 0.f);
    float v1 = fmaxf(__builtin_fmaf(acc[i][1], a, bo), 0.f);
    float v2 = fmaxf(__builtin_fmaf(acc[i][2], a, bo), 0.f);
    float v3 = fmaxf(__builtin_fmaf(acc[i][3], a, bo), 0.f);
    float m = fmaxf(fmaxf(v0, v1), fmaxf(v2, v3));
    m = fmaxf(m, __shfl_xor(m, 16, 64));
    m = fmaxf(m, __shfl_xor(m, 32, 64));
    mx[i] = m;
  }
  float* s_part = &twt[0][0];
  __syncthreads();
  const int lane = t & 63, w = t >> 6;
  if (lane < 16) {
#pragma unroll
    for (int i = 0; i < 8; ++i) s_part[w * 128 + to * 8 + i] = mx[i];
  }
  __syncthreads();
  if (t < 128) {
    const float mm = fmaxf(fmaxf(s_part[t], s_part[128 + t]),
                           fmaxf(s_part[256 + t], s_part[384 + t]));
    atomicMax((int*)pooled + (size_t)b * 1024 + o0 + t, __float_as_int(mm));
  }
}

// ---------------- head: FC1 + BN6 + ReLU ----------------
__global__ __launch_bounds__(256) void k_head1(const float* __restrict__ pooled, const float* __restrict__ lw1,
                        const float* __restrict__ g6, const float* __restrict__ b6,
                        float* __restrict__ sh) {
  const int wv   = threadIdx.x >> 6;
  const int lane = threadIdx.x & 63;
  const int o    = blockIdx.x * 4 + wv;
  const float* __restrict__ wr = lw1 + (size_t)o * 1024;
  float y0 = 0, y1 = 0, y2 = 0, y3 = 0;
  for (int c = lane; c < 1024; c += 64) {
    const float wvv = wr[c];
    y0 = __builtin_fmaf(wvv, pooled[c], y0);
    y1 = __builtin_fmaf(wvv, pooled[1024 + c], y1);
    y2 = __builtin_fmaf(wvv, pooled[2048 + c], y2);
    y3 = __builtin_fmaf(wvv, pooled[3072 + c], y3);
  }
#pragma unroll
  for (int off = 32; off >= 1; off >>= 1) {
    y0 += __shfl_xor(y0, off, 64);
    y1 += __shfl_xor(y1, off, 64);
    y2 += __shfl_xor(y2, off, 64);
    y3 += __shfl_xor(y3, off, 64);
  }
  if (lane == 0) {
    const float mu = 0.25f * (y0 + y1 + y2 + y3);
    const float d0 = y0 - mu, d1 = y1 - mu, d2 = y2 - mu, d3 = y3 - mu;
    const float var = 0.25f * (d0 * d0 + d1 * d1 + d2 * d2 + d3 * d3);
    const float a = g6[o] / sqrtf(var + EPSV);
    const float bc = b6[o];
    sh[o]        = fmaxf(__builtin_fmaf(d0, a, bc), 0.f);
    sh[512 + o]  = fmaxf(__builtin_fmaf(d1, a, bc), 0.f);
    sh[1024 + o] = fmaxf(__builtin_fmaf(d2, a, bc), 0.f);
    sh[1536 + o] = fmaxf(__builtin_fmaf(d3, a, bc), 0.f);
  }
}

// ---------------- head: FC2 ----------------
__global__ void k_head2(const float* __restrict__ sh, const float* __restrict__ lw2,
                        const float* __restrict__ lb2, float* __restrict__ out) {
  const int wv   = threadIdx.x >> 6;
  const int lane = threadIdx.x & 63;
  float s0 = 0, s1 = 0, s2 = 0, s3 = 0;
  for (int c = lane; c < 512; c += 64) {
    const float h = sh[wv * 512 + c];
    s0 = __builtin_fmaf(lw2[c], h, s0);
    s1 = __builtin_fmaf(lw2[512 + c], h, s1);
    s2 = __builtin_fmaf(lw2[1024 + c], h, s2);
    s3 = __builtin_fmaf(lw2[1536 + c], h, s3);
  }
#pragma unroll
  for (int off = 32; off >= 1; off >>= 1) {
    s0 += __shfl_xor(s0, off, 64);
    s1 += __shfl_xor(s1, off, 64);
    s2 += __shfl_xor(s2, off, 64);
    s3 += __shfl_xor(s3, off, 64);
  }
  if (lane == 0) {
    out[wv * 4 + 0] = s0 + lb2[0];
    out[wv * 4 + 1] = s1 + lb2[1];
    out[wv * 4 + 2] = s2 + lb2[2];
    out[wv * 4 + 3] = s3 + lb2[3];
  }
}

extern "C" void kernel_launch(void* const* d_in, const int* in_sizes, int n_in,
                              void* d_out, int out_size, void* d_ws, size_t ws_size,
                              hipStream_t stream) {
  (void)in_sizes; (void)n_in; (void)out_size; (void)ws_size;
  const float* x    = (const float*)d_in[0];
  const void*  lidx = d_in[1];
  const float* w1 = (const float*)d_in[3];
  const float* w2 = (const float*)d_in[4];
  const float* w3 = (const float*)d_in[5];
  const float* w4 = (const float*)d_in[6];
  const float* w5 = (const float*)d_in[7];
  const float* g1 = (const float*)d_in[8],  *b1 = (const float*)d_in[9];
  const float* g2 = (const float*)d_in[10], *b2 = (const float*)d_in[11];
  const float* g3 = (const float*)d_in[12], *b3 = (const float*)d_in[13];
  const float* g4 = (const float*)d_in[14], *b4 = (const float*)d_in[15];
  const float* g5 = (const float*)d_in[16], *b5 = (const float*)d_in[17];
  const float* lw1 = (const float*)d_in[18];
  const float* g6 = (const float*)d_in[19], *b6 = (const float*)d_in[20];
  const float* lw2 = (const float*)d_in[21], *lb2 = (const float*)d_in[22];
  float* out = (float*)d_out;
  float* ws  = (float*)d_ws;

  hipMemsetAsync(ws + OFF_M0, 0, (OFF_ZEND - OFF_M0) * sizeof(float), stream);

  k_prep<<<4, 256, 0, stream>>>((const unsigned int*)lidx, (int*)(ws + OFF_MODE),
                                (int*)(ws + OFF_PCNT), (float4*)(ws + OFF_PL), x);
  k_wtall<<<579, 256, 0, stream>>>(w1, w2, w3, w4, w5, ws + OFF_WT1, ws + OFF_WT2,
                                   ws + OFF_WT3, ws + OFF_WT4, ws + OFF_WT5);
  k_knn<<<2048, 256, 0, stream>>>(x, (const float4*)(ws + OFF_PL),
                                  (const int*)(ws + OFF_PCNT), ws + OFF_H0);

  k_stats_small<12><<<128, 256, 0, stream>>>(ws + OFF_H0, ws + OFF_M0, ws + OFF_S0);
  k_solve<12, 64><<<16, 256, 0, stream>>>(w1, g1, b1, ws + OFF_M0, ws + OFF_S0,
                                          ws + OFF_A1, ws + OFF_B1);
  k_cgemm<12, 64><<<512, 256, 0, stream>>>(ws + OFF_H0, ws + OFF_WT1,
                                           ws + OFF_A1, ws + OFF_B1, ws + OFF_H1);

  k_stats<64><<<256, 512, 0, stream>>>(ws + OFF_H1, ws + OFF_P64);
  k_sred<64><<<9, 256, 0, stream>>>(ws + OFF_P64, ws + OFF_M1, ws + OFF_S1);
  k_solve<64, 64><<<16, 256, 0, stream>>>(w2, g2, b2, ws + OFF_M1, ws + OFF_S1,
                                          ws + OFF_A2, ws + OFF_B2);
  k_cgemm<64, 64><<<512, 256, 0, stream>>>(ws + OFF_H1, ws + OFF_WT2,
                                           ws + OFF_A2, ws + OFF_B2, ws + OFF_H2);

  k_stats<64><<<256, 512, 0, stream>>>(ws + OFF_H2, ws + OFF_P64);
  k_sred<64><<<9, 256, 0, stream>>>(ws + OFF_P64, ws + OFF_M2, ws + OFF_S2);
  k_solve<64, 64><<<16, 256, 0, stream>>>(w3, g3, b3, ws + OFF_M2, ws + OFF_S2,
                                          ws + OFF_A3, ws + OFF_B3);
  k_cgemm<64, 64><<<512, 256, 0, stream>>>(ws + OFF_H2, ws + OFF_WT3,
                                           ws + OFF_A3, ws + OFF_B3, ws + OFF_H3);

  k_stats<64><<<256, 512, 0, stream>>>(ws + OFF_H3, ws + OFF_P64);
  k_sred<64><<<9, 256, 0, stream>>>(ws + OFF_P64, ws + OFF_M3, ws + OFF_S3);
  k_solve<64, 128><<<32, 256, 0, stream>>>(w4, g4, b4, ws + OFF_M3, ws + OFF_S3,
                                           ws + OFF_A4, ws + OFF_B4);
  k_cgemm<64, 128><<<1024, 256, 0, stream>>>(ws + OFF_H3, ws + OFF_WT4,
                                             ws + OFF_A4, ws + OFF_B4, ws + OFF_H4);

  k_stats<128><<<256, 512, 0, stream>>>(ws + OFF_H4, ws + OFF_P128);
  k_sred<128><<<35, 256, 0, stream>>>(ws + OFF_P128, ws + OFF_M4, ws + OFF_S4);
  k_solve<128, 1024><<<256, 256, 0, stream>>>(w5, g5, b5, ws + OFF_M4, ws + OFF_S4,
                                              ws + OFF_A5, ws + OFF_B5);
  k_cgemm5<<<4096, 256, 0, stream>>>(ws + OFF_H4, ws + OFF_WT5,
                                     ws + OFF_A5, ws + OFF_B5, ws + OFF_POOL);

  k_head1<<<128, 256, 0, stream>>>(ws + OFF_POOL, lw1, g6, b6, ws + OFF_SH);
  k_head2<<<1, 256, 0, stream>>>(ws + OFF_SH, lw2, lb2, out);
}

// Round 9
// 549.951 us; speedup vs baseline: 1.2035x; 1.2035x over previous
//
#include <hip/hip_runtime.h>

constexpr int BB = 4, NN = 8192, KNB = 20;
constexpr int BN_ = BB * NN; // 32768
constexpr float EPSV = 1e-5f;

// ---------------- workspace layout (float offsets) ----------------
constexpr size_t OFF_MODE  = 0;                     // int mode
constexpr size_t OFF_PCNT  = 16;                    // int[4]
constexpr size_t OFF_PL    = 64;                    // float4[4][8192] = 131072 floats
constexpr size_t OFF_M0 = OFF_PL + 131072;          // zero region start
constexpr size_t OFF_S0 = OFF_M0 + 12;
constexpr size_t OFF_M1 = OFF_S0 + 144;
constexpr size_t OFF_S1 = OFF_M1 + 64;
constexpr size_t OFF_M2 = OFF_S1 + 64 * 64;
constexpr size_t OFF_S2 = OFF_M2 + 64;
constexpr size_t OFF_M3 = OFF_S2 + 64 * 64;
constexpr size_t OFF_S3 = OFF_M3 + 64;
constexpr size_t OFF_M4 = OFF_S3 + 64 * 64;
constexpr size_t OFF_S4 = OFF_M4 + 128;
constexpr size_t OFF_POOL = OFF_S4 + 128 * 128;
constexpr size_t OFF_ZEND = OFF_POOL + BB * 1024;   // zero region end
constexpr size_t OFF_A1 = OFF_ZEND;
constexpr size_t OFF_B1 = OFF_A1 + 64;
constexpr size_t OFF_A2 = OFF_B1 + 64;
constexpr size_t OFF_B2 = OFF_A2 + 64;
constexpr size_t OFF_A3 = OFF_B2 + 64;
constexpr size_t OFF_B3 = OFF_A3 + 64;
constexpr size_t OFF_A4 = OFF_B3 + 64;
constexpr size_t OFF_B4 = OFF_A4 + 128;
constexpr size_t OFF_A5 = OFF_B4 + 128;
constexpr size_t OFF_B5 = OFF_A5 + 1024;
constexpr size_t OFF_SH = OFF_B5 + 1024;            // 4*512
constexpr size_t OFF_WT1 = OFF_SH + BB * 512;       // [12][64]
constexpr size_t OFF_WT2 = OFF_WT1 + 768;           // [64][64]
constexpr size_t OFF_WT3 = OFF_WT2 + 4096;          // [64][64]
constexpr size_t OFF_WT4 = OFF_WT3 + 4096;          // [64][128]
constexpr size_t OFF_WT5_RAW = OFF_WT4 + 8192;
constexpr size_t OFF_WT5 = (OFF_WT5_RAW + 63) & ~size_t(63);  // [128][1024]
constexpr size_t OFF_H0_RAW = OFF_WT5 + 1024 * 128;
constexpr size_t OFF_H0 = (OFF_H0_RAW + 63) & ~size_t(63);  // [4][12][8192]
constexpr size_t OFF_H1 = OFF_H0 + (size_t)BB * 12 * NN;    // [4][64][8192]
constexpr size_t OFF_H2 = OFF_H1 + (size_t)BB * 64 * NN;    // [4][64][8192]
constexpr size_t OFF_H3 = OFF_H1;                           // alias (h1 dead)
constexpr size_t OFF_H4 = OFF_H2 + (size_t)BB * 64 * NN;    // [4][128][8192]
constexpr size_t OFF_P64  = OFF_H4;
constexpr size_t OFF_P128 = OFF_H1;
constexpr size_t WS_FLOATS = OFF_H4 + (size_t)BB * 128 * NN;

__device__ inline float dist3(const float4 c, float x0, float x1, float x2) {
  const float d0 = c.x - x0, d1 = c.y - x1, d2 = c.z - x2;
  return __builtin_fmaf(d0, d0, __builtin_fmaf(d1, d1, d2 * d2));
}

// ---------------- prep: detect bool storage, compact local points ----------------
__global__ __launch_bounds__(256) void k_prep(const unsigned int* __restrict__ li32,
                                              int* __restrict__ mode,
                                              int* __restrict__ pcnt,
                                              float4* __restrict__ pl,
                                              const float* __restrict__ x) {
  const int b = blockIdx.x;
  const int t = threadIdx.x;
  const int lane = t & 63;
  const int w = t >> 6;
  __shared__ int s_wc[4];
  __shared__ int s_base;
  __shared__ int s_any;
  if (t == 0) { s_base = 0; s_any = 0; }
  __syncthreads();
  unsigned int any = 0;
  for (int i = t; i < 2048; i += 256) any |= (li32[b * 2048 + i] > 1u) ? 1u : 0u;
  if (any) atomicOr(&s_any, 1);
  __syncthreads();
  const int md = s_any;   // 1 => stored as bytes
  if (b == 0 && t == 0) *mode = md;
  const unsigned char* p8 = (const unsigned char*)li32;
  const float* __restrict__ xb = x + (size_t)b * 3 * NN;
  for (int j0 = 0; j0 < NN; j0 += 256) {
    const int m = j0 + t;
    const int f = md ? (p8[b * NN + m] != 0) : (li32[b * NN + m] != 0);
    const unsigned long long mask = __ballot(f);
    const int pos = __popcll(mask & ((1ull << lane) - 1ull));
    if (lane == 0) s_wc[w] = (int)__popcll(mask);
    __syncthreads();
    int off = s_base;
    for (int ww = 0; ww < w; ++ww) off += s_wc[ww];
    const int tot = s_wc[0] + s_wc[1] + s_wc[2] + s_wc[3];
    if (f) pl[(size_t)b * NN + off + pos] =
        make_float4(xb[m], xb[NN + m], xb[2 * NN + m], __int_as_float(m));
    __syncthreads();
    if (t == 0) s_base += tot;
    __syncthreads();
  }
  if (t == 0) pcnt[b] = s_base;
}

// ---------------- transpose all weights: wtX[c][o] ----------------
__global__ void k_wtall(const float* __restrict__ w1, const float* __restrict__ w2,
                        const float* __restrict__ w3, const float* __restrict__ w4,
                        const float* __restrict__ w5, float* __restrict__ wt1,
                        float* __restrict__ wt2, float* __restrict__ wt3,
                        float* __restrict__ wt4, float* __restrict__ wt5) {
  const int i = blockIdx.x * 256 + threadIdx.x;
  if (i < 768)        { const int o = i / 12,  c = i % 12;  wt1[c * 64 + o]  = w1[i]; }
  else if (i < 4864)  { const int j = i - 768;  const int o = j >> 6, c = j & 63;  wt2[c * 64 + o]  = w2[j]; }
  else if (i < 8960)  { const int j = i - 4864; const int o = j >> 6, c = j & 63;  wt3[c * 64 + o]  = w3[j]; }
  else if (i < 17152) { const int j = i - 8960; const int o = j >> 6, c = j & 63;  wt4[c * 128 + o] = w4[j]; }
  else if (i < 148224){ const int j = i - 17152;const int o = j >> 7, c = j & 127; wt5[c * 1024 + o] = w5[j]; }
}

// ---------------- kNN + covariance -> h0 [4][12][8192] ----------------
// 512 blocks x 512 threads: 64 queries (lane) x 8 partitions (wave).
// Candidates processed 4-wide (wave-uniform scalar loads batch; ballot
// amortized). Phase 1: deferral buffer (cap 12, flush at bc>=8). Phase 2:
// inline moments for d<T, ties at T recorded by index.
__global__ __launch_bounds__(512) void k_knn(const float* __restrict__ x,
                                             const float4* __restrict__ pl,
                                             const int* __restrict__ pcnt,
                                             float* __restrict__ h0) {
  const int blk  = blockIdx.x;
  const int b    = blk >> 7;
  const int tile = blk & 127;
  const int t    = threadIdx.x;
  const int lane = t & 63;
  const int w    = __builtin_amdgcn_readfirstlane(t >> 6);
  const int n    = tile * 64 + lane;

  __shared__ float s_pool[8 * 64 * 21];   // 43KB; first 24KB alias dbuf[12][512]
  __shared__ float s_T[64];
  __shared__ float s_red[64][13];
  __shared__ int   s_tc[64];
  __shared__ int   s_ti[64][24];
  float* __restrict__ s_dbuf = s_pool;

  const float* __restrict__ xb  = x + (size_t)b * 3 * NN;
  const float4* __restrict__ plb = pl + (size_t)b * NN;
  const int cnt = pcnt[b];
  const float xn0 = xb[n], xn1 = xb[NN + n], xn2 = xb[2 * NN + n];

  const int jlo = (cnt * w) >> 3;
  const int jhi = (cnt * (w + 1)) >> 3;

  float tk[KNB];
#pragma unroll
  for (int i = 0; i < KNB; ++i) tk[i] = 3.0e38f;

  // ---- phase 1: buffered top-20 distances, 4-wide scan ----
  {
    float thr = 3.0e38f;
    int bc = 0;
    int j = jlo;
    for (; j + 3 < jhi; j += 4) {
      const float4 c0 = plb[j],     c1 = plb[j + 1];
      const float4 c2 = plb[j + 2], c3 = plb[j + 3];
      const float d0 = dist3(c0, xn0, xn1, xn2);
      const float d1 = dist3(c1, xn0, xn1, xn2);
      const float d2 = dist3(c2, xn0, xn1, xn2);
      const float d3 = dist3(c3, xn0, xn1, xn2);
      if (d0 < thr) { s_dbuf[bc * 512 + t] = d0; ++bc; }
      if (d1 < thr) { s_dbuf[bc * 512 + t] = d1; ++bc; }
      if (d2 < thr) { s_dbuf[bc * 512 + t] = d2; ++bc; }
      if (d3 < thr) { s_dbuf[bc * 512 + t] = d3; ++bc; }
      if (__any(bc >= 8)) {
        for (int i = 0; i < bc; ++i) {
          float dv = s_dbuf[i * 512 + t];
          if (dv < tk[KNB - 1]) {
#pragma unroll
            for (int q2 = 0; q2 < KNB; ++q2) {
              const float lo = fminf(tk[q2], dv);
              dv = fmaxf(tk[q2], dv);
              tk[q2] = lo;
            }
          }
        }
        bc = 0;
        thr = tk[KNB - 1];
      }
    }
    for (; j < jhi; ++j) {          // tail (<=3): bc <= 7+3+... <= 10 < 12
      const float4 c = plb[j];
      const float d = dist3(c, xn0, xn1, xn2);
      if (d < thr) { s_dbuf[bc * 512 + t] = d; ++bc; }
    }
    for (int i = 0; i < bc; ++i) {  // final flush
      float dv = s_dbuf[i * 512 + t];
      if (dv < tk[KNB - 1]) {
#pragma unroll
        for (int q2 = 0; q2 < KNB; ++q2) {
          const float lo = fminf(tk[q2], dv);
          dv = fmaxf(tk[q2], dv);
          tk[q2] = lo;
        }
      }
    }
  }
  __syncthreads();   // dbuf dead; lists may overwrite

  {
    const int base = (w * 64 + lane) * 21;
#pragma unroll
    for (int i = 0; i < KNB; ++i) s_pool[base + i] = tk[i];
    s_pool[base + KNB] = 3.0e38f;
  }
  __syncthreads();

  if (w == 0) {  // 8-way merge -> exact 20th smallest
    int i0 = 0, i1 = 0, i2 = 0, i3 = 0, i4 = 0, i5 = 0, i6 = 0, i7 = 0;
    float T = 0.f;
    for (int c = 0; c < KNB; ++c) {
      const float v0 = s_pool[(0 * 64 + lane) * 21 + i0];
      const float v1 = s_pool[(1 * 64 + lane) * 21 + i1];
      const float v2 = s_pool[(2 * 64 + lane) * 21 + i2];
      const float v3 = s_pool[(3 * 64 + lane) * 21 + i3];
      const float v4 = s_pool[(4 * 64 + lane) * 21 + i4];
      const float v5 = s_pool[(5 * 64 + lane) * 21 + i5];
      const float v6 = s_pool[(6 * 64 + lane) * 21 + i6];
      const float v7 = s_pool[(7 * 64 + lane) * 21 + i7];
      float best = fminf(fminf(fminf(v0, v1), fminf(v2, v3)),
                         fminf(fminf(v4, v5), fminf(v6, v7)));
      int adv, taken;
      adv = (v0 == best) ? 1 : 0;           i0 += adv; taken = adv;
      adv = (!taken && v1 == best) ? 1 : 0; i1 += adv; taken |= adv;
      adv = (!taken && v2 == best) ? 1 : 0; i2 += adv; taken |= adv;
      adv = (!taken && v3 == best) ? 1 : 0; i3 += adv; taken |= adv;
      adv = (!taken && v4 == best) ? 1 : 0; i4 += adv; taken |= adv;
      adv = (!taken && v5 == best) ? 1 : 0; i5 += adv; taken |= adv;
      adv = (!taken && v6 == best) ? 1 : 0; i6 += adv; taken |= adv;
      adv = (!taken && v7 == best) ? 1 : 0; i7 += adv;
      T = best;
    }
    s_T[lane] = T;
    s_tc[lane] = 0;
  }
  __syncthreads();
  const float T = s_T[lane];

  // ---- phase 2: inline moments for d<T, ties at T by index; 4-wide ----
  float sx = 0, sy = 0, sz = 0;
  float xx = 0, xy = 0, xz = 0, yy = 0, yz = 0, zz = 0;
  float clf = 0;
  {
    int j = jlo;
    for (; j + 3 < jhi; j += 4) {
      const float4 c0 = plb[j],     c1 = plb[j + 1];
      const float4 c2 = plb[j + 2], c3 = plb[j + 3];
      const float d0 = dist3(c0, xn0, xn1, xn2);
      const float d1 = dist3(c1, xn0, xn1, xn2);
      const float d2 = dist3(c2, xn0, xn1, xn2);
      const float d3 = dist3(c3, xn0, xn1, xn2);
      if (d0 < T) {
        clf += 1.f; sx += c0.x; sy += c0.y; sz += c0.z;
        xx = __builtin_fmaf(c0.x, c0.x, xx); xy = __builtin_fmaf(c0.x, c0.y, xy);
        xz = __builtin_fmaf(c0.x, c0.z, xz); yy = __builtin_fmaf(c0.y, c0.y, yy);
        yz = __builtin_fmaf(c0.y, c0.z, yz); zz = __builtin_fmaf(c0.z, c0.z, zz);
      } else if (d0 == T) {
        const int pos = atomicAdd(&s_tc[lane], 1);
        if (pos < 24) s_ti[lane][pos] = j;
      }
      if (d1 < T) {
        clf += 1.f; sx += c1.x; sy += c1.y; sz += c1.z;
        xx = __builtin_fmaf(c1.x, c1.x, xx); xy = __builtin_fmaf(c1.x, c1.y, xy);
        xz = __builtin_fmaf(c1.x, c1.z, xz); yy = __builtin_fmaf(c1.y, c1.y, yy);
        yz = __builtin_fmaf(c1.y, c1.z, yz); zz = __builtin_fmaf(c1.z, c1.z, zz);
      } else if (d1 == T) {
        const int pos = atomicAdd(&s_tc[lane], 1);
        if (pos < 24) s_ti[lane][pos] = j + 1;
      }
      if (d2 < T) {
        clf += 1.f; sx += c2.x; sy += c2.y; sz += c2.z;
        xx = __builtin_fmaf(c2.x, c2.x, xx); xy = __builtin_fmaf(c2.x, c2.y, xy);
        xz = __builtin_fmaf(c2.x, c2.z, xz); yy = __builtin_fmaf(c2.y, c2.y, yy);
        yz = __builtin_fmaf(c2.y, c2.z, yz); zz = __builtin_fmaf(c2.z, c2.z, zz);
      } else if (d2 == T) {
        const int pos = atomicAdd(&s_tc[lane], 1);
        if (pos < 24) s_ti[lane][pos] = j + 2;
      }
      if (d3 < T) {
        clf += 1.f; sx += c3.x; sy += c3.y; sz += c3.z;
        xx = __builtin_fmaf(c3.x, c3.x, xx); xy = __builtin_fmaf(c3.x, c3.y, xy);
        xz = __builtin_fmaf(c3.x, c3.z, xz); yy = __builtin_fmaf(c3.y, c3.y, yy);
        yz = __builtin_fmaf(c3.y, c3.z, yz); zz = __builtin_fmaf(c3.z, c3.z, zz);
      } else if (d3 == T) {
        const int pos = atomicAdd(&s_tc[lane], 1);
        if (pos < 24) s_ti[lane][pos] = j + 3;
      }
    }
    for (; j < jhi; ++j) {
      const float4 c = plb[j];
      const float d = dist3(c, xn0, xn1, xn2);
      if (d < T) {
        clf += 1.f; sx += c.x; sy += c.y; sz += c.z;
        xx = __builtin_fmaf(c.x, c.x, xx); xy = __builtin_fmaf(c.x, c.y, xy);
        xz = __builtin_fmaf(c.x, c.z, xz); yy = __builtin_fmaf(c.y, c.y, yy);
        yz = __builtin_fmaf(c.y, c.z, yz); zz = __builtin_fmaf(c.z, c.z, zz);
      } else if (d == T) {
        const int pos = atomicAdd(&s_tc[lane], 1);
        if (pos < 24) s_ti[lane][pos] = j;
      }
    }
  }
  __syncthreads();   // phase-2 done before partials overwrite s_pool
  {
    const int base = (w * 64 + lane) * 13;
    s_pool[base + 0] = sx; s_pool[base + 1] = sy; s_pool[base + 2] = sz;
    s_pool[base + 3] = xx; s_pool[base + 4] = xy; s_pool[base + 5] = xz;
    s_pool[base + 6] = yy; s_pool[base + 7] = yz; s_pool[base + 8] = zz;
    s_pool[base + 9] = clf;
  }
  __syncthreads();
  {
    const int q = t & 63, a = t >> 6;
    float s = 0.f;
#pragma unroll
    for (int wv = 0; wv < 8; ++wv) s += s_pool[(wv * 64 + q) * 13 + a];
    s_red[q][a] = s;
    if (a < 2) {
      const int a2 = a + 8;
      float s2 = 0.f;
#pragma unroll
      for (int wv = 0; wv < 8; ++wv) s2 += s_pool[(wv * 64 + q) * 13 + a2];
      s_red[q][a2] = s2;
    }
  }
  __syncthreads();

  if (w == 0) {
    float fsx = s_red[lane][0], fsy = s_red[lane][1], fsz = s_red[lane][2];
    float fxx = s_red[lane][3], fxy = s_red[lane][4], fxz = s_red[lane][5];
    float fyy = s_red[lane][6], fyz = s_red[lane][7], fzz = s_red[lane][8];
    const int cl = (int)s_red[lane][9];
    const int r = KNB - cl;
    const int tc = min(s_tc[lane], 24);
    int kk = cl;
    int prev = -1;
    for (int s = 0; s < r; ++s) {
      int best = 0x7fffffff;
      for (int u = 0; u < tc; ++u) {
        const int mi2 = s_ti[lane][u];
        if (mi2 > prev && mi2 < best) best = mi2;
      }
      if (best == 0x7fffffff) break;
      const float4 pp = plb[best];
      fsx += pp.x; fsy += pp.y; fsz += pp.z;
      fxx = __builtin_fmaf(pp.x, pp.x, fxx);
      fxy = __builtin_fmaf(pp.x, pp.y, fxy);
      fxz = __builtin_fmaf(pp.x, pp.z, fxz);
      fyy = __builtin_fmaf(pp.y, pp.y, fyy);
      fyz = __builtin_fmaf(pp.y, pp.z, fyz);
      fzz = __builtin_fmaf(pp.z, pp.z, fzz);
      prev = best;
      ++kk;
    }
    const float kf = (float)max(kk, 1);
    const float inv = 1.0f / kf;
    const float mx = fsx * inv, my = fsy * inv, mz = fsz * inv;
    const float c00 = fxx - kf * mx * mx;
    const float c01 = fxy - kf * mx * my;
    const float c02 = fxz - kf * mx * mz;
    const float c11 = fyy - kf * my * my;
    const float c12 = fyz - kf * my * mz;
    const float c22 = fzz - kf * mz * mz;
    float* __restrict__ op = h0 + (size_t)b * 12 * NN + n;
    op[0] = xn0; op[(size_t)NN] = xn1; op[(size_t)2 * NN] = xn2;
    op[(size_t)3 * NN] = c00; op[(size_t)4 * NN]  = c01; op[(size_t)5 * NN]  = c02;
    op[(size_t)6 * NN] = c01; op[(size_t)7 * NN]  = c11; op[(size_t)8 * NN]  = c12;
    op[(size_t)9 * NN] = c02; op[(size_t)10 * NN] = c12; op[(size_t)11 * NN] = c22;
  }
}

// ---------------- stats (small C) ----------------
template <int C>
__global__ __launch_bounds__(256) void k_stats_small(const float* __restrict__ h,
                                                     float* __restrict__ mo,
                                                     float* __restrict__ So) {
  constexpr int NP  = C * (C + 1) / 2;
  constexpr int KPT = (NP + 255) / 256;
  __shared__ float tile[C][65];
  const int t = threadIdx.x;
  float acc[KPT];
#pragma unroll
  for (int e = 0; e < KPT; ++e) acc[e] = 0.f;
  float accm = 0.f;
  for (int tl = blockIdx.x; tl < BN_ / 64; tl += gridDim.x) {
    const int b  = tl >> 7;
    const int p0 = (tl & 127) * 64;
    for (int idx = t; idx < C * 64; idx += 256) {
      const int c = idx >> 6, p = idx & 63;
      tile[c][p] = h[((size_t)b * C + c) * NN + p0 + p];
    }
    __syncthreads();
    {
      int ii = 0, rem = t;
#pragma unroll
      for (int e = 0; e < KPT; ++e) {
        const int lin = t + 256 * e;
        if (lin < NP) {
          while (rem >= C - ii) { rem -= C - ii; ++ii; }
          const int jj = ii + rem;
          float s = 0.f;
#pragma unroll 8
          for (int p = 0; p < 64; ++p) s = __builtin_fmaf(tile[ii][p], tile[jj][p], s);
          acc[e] += s;
        }
        rem += 256;
      }
    }
    if (t < C) {
      float s = 0.f;
#pragma unroll 8
      for (int p = 0; p < 64; ++p) s += tile[t][p];
      accm += s;
    }
    __syncthreads();
  }
  {
    int ii = 0, rem = t;
#pragma unroll
    for (int e = 0; e < KPT; ++e) {
      const int lin = t + 256 * e;
      if (lin < NP) {
        while (rem >= C - ii) { rem -= C - ii; ++ii; }
        atomicAdd(&So[ii * C + ii + rem], acc[e]);
      }
      rem += 256;
    }
  }
  if (t < C) atomicAdd(&mo[t], accm);
}

// ---------------- stats stage A (C=64/128): per-block partials ----------------
template <int C>
__global__ __launch_bounds__(512) void k_stats(const float* __restrict__ h,
                                               float* __restrict__ part) {
  constexpr int G      = (C == 128) ? 8 : 4;
  constexpr int NPB    = 136 * G * G;
  constexpr int ROWLEN = NPB + C;
  constexpr int STR    = C + 4;
  __shared__ float ht[128][STR];
  __shared__ float red[136][G * G];
  const int t   = threadIdx.x;
  const int blk = blockIdx.x;
  const int b   = blk >> 6;
  const int p0  = (blk & 63) * 128;
  for (int i = t; i < C * 128; i += 512) {
    const int c = i >> 7, p = i & 127;
    ht[p][c] = h[((size_t)b * C + c) * NN + p0 + p];
  }
  __syncthreads();
  const int s  = t >> 8;
  const int pb = t & 255;
  const int bi = pb & 15;
  const int bj = pb >> 4;
  const bool act = (bi <= bj);
  float acc[G * G];
#pragma unroll
  for (int g = 0; g < G * G; ++g) acc[g] = 0.f;
  if (act) {
    for (int p = s * 64; p < s * 64 + 64; ++p) {
      float a[G], bv[G];
      *(float4*)&a[0] = *(const float4*)&ht[p][bi * G];
      *(float4*)&bv[0] = *(const float4*)&ht[p][bj * G];
      if constexpr (G == 8) {
        *(float4*)&a[4] = *(const float4*)&ht[p][bi * G + 4];
        *(float4*)&bv[4] = *(const float4*)&ht[p][bj * G + 4];
      }
#pragma unroll
      for (int gi = 0; gi < G; ++gi)
#pragma unroll
        for (int gj = 0; gj < G; ++gj)
          acc[gi * G + gj] = __builtin_fmaf(a[gi], bv[gj], acc[gi * G + gj]);
    }
  }
  const int rank = bj * (bj + 1) / 2 + bi;
  if (s == 1 && act) {
#pragma unroll
    for (int g = 0; g < G * G; ++g) red[rank][g] = acc[g];
  }
  __syncthreads();
  float* __restrict__ prow = part + (size_t)blk * ROWLEN;
  if (s == 0 && act) {
#pragma unroll
    for (int g = 0; g < G * G; g += 4) {
      float4 v;
      v.x = acc[g + 0] + red[rank][g + 0];
      v.y = acc[g + 1] + red[rank][g + 1];
      v.z = acc[g + 2] + red[rank][g + 2];
      v.w = acc[g + 3] + red[rank][g + 3];
      *(float4*)&prow[rank * G * G + g] = v;
    }
  }
  if (t < C) {
    float sm = 0.f;
#pragma unroll 8
    for (int p = 0; p < 128; ++p) sm += ht[p][t];
    prow[NPB + t] = sm;
  }
}

// ---------------- stats stage B ----------------
template <int C>
__global__ __launch_bounds__(256) void k_sred(const float* __restrict__ part,
                                              float* __restrict__ mo,
                                              float* __restrict__ So) {
  constexpr int G      = (C == 128) ? 8 : 4;
  constexpr int GG     = G * G;
  constexpr int NPB    = 136 * GG;
  constexpr int ROWLEN = NPB + C;
  const int e = blockIdx.x * 256 + threadIdx.x;
  if (e >= ROWLEN) return;
  const float* __restrict__ p = part + e;
  float s = 0.f;
#pragma unroll 8
  for (int r = 0; r < 256; ++r) s += p[(size_t)r * ROWLEN];
  if (e < NPB) {
    const int rank = e / GG;
    const int g    = e - rank * GG;
    int bj = 0;
    while ((bj + 1) * (bj + 2) / 2 <= rank) ++bj;
    const int bi = rank - bj * (bj + 1) / 2;
    const int gi = g / G, gj = g - gi * G;
    So[(bi * G + gi) * C + (bj * G + gj)] = s;
  } else {
    mo[e - NPB] = s;
  }
}

// ---------------- solve BN affine ----------------
template <int CIN, int COUT>
__global__ __launch_bounds__(256) void k_solve(const float* __restrict__ w, const float* __restrict__ g,
                        const float* __restrict__ bb, const float* __restrict__ m,
                        const float* __restrict__ S, float* __restrict__ A,
                        float* __restrict__ Bc) {
  const int wv   = threadIdx.x >> 6;
  const int lane = threadIdx.x & 63;
  const int o    = blockIdx.x * 4 + wv;
  if (o >= COUT) return;
  const float* __restrict__ wr = w + (size_t)o * CIN;
  float mu = 0.f;
  for (int i = lane; i < CIN; i += 64) mu = __builtin_fmaf(wr[i], m[i], mu);
  float e2 = 0.f;
#pragma unroll 4
  for (int lin = lane; lin < CIN * CIN; lin += 64) {
    const int i = lin / CIN;
    const int j = lin - i * CIN;
    const int lo = min(i, j), hi = max(i, j);
    e2 = __builtin_fmaf(wr[i] * wr[j], S[lo * CIN + hi], e2);
  }
#pragma unroll
  for (int off = 32; off >= 1; off >>= 1) {
    mu += __shfl_xor(mu, off, 64);
    e2 += __shfl_xor(e2, off, 64);
  }
  if (lane == 0) {
    mu *= (1.0f / BN_);
    e2 *= (1.0f / BN_);
    const float var = e2 - mu * mu;
    const float a = g[o] / sqrtf(var + EPSV);
    A[o] = a;
    Bc[o] = bb[o] - mu * a;
  }
}

// ---------------- conv GEMM: 64o x 64p tile, thread 4o x 4p ----------------
template <int CIN, int COUT>
__global__ __launch_bounds__(256) void k_cgemm(const float* __restrict__ hin,
                                               const float* __restrict__ wt, // [CIN][COUT]
                                               const float* __restrict__ A,
                                               const float* __restrict__ Bc,
                                               float* __restrict__ outp) {
  constexpr int nOT = COUT / 64;
  __shared__ float tin[CIN][64];
  __shared__ float twt[CIN][64];
  const int blk = blockIdx.x;
  const int ot  = blk % nOT;
  const int pt  = blk / nOT;
  const int b   = pt >> 7;
  const int p0  = (pt & 127) * 64;
  const int o0  = ot * 64;
  const int t   = threadIdx.x;

  for (int i = t; i < CIN * 16; i += 256) {
    const int c = i >> 4, sgm = i & 15;
    *(float4*)&tin[c][sgm * 4] =
        *(const float4*)&hin[((size_t)b * CIN + c) * NN + p0 + sgm * 4];
    *(float4*)&twt[c][sgm * 4] =
        *(const float4*)&wt[(size_t)c * COUT + o0 + sgm * 4];
  }
  __syncthreads();

  const int to = t & 15;
  const int tp = t >> 4;
  float acc[4][4];
#pragma unroll
  for (int i = 0; i < 4; ++i)
#pragma unroll
    for (int j = 0; j < 4; ++j) acc[i][j] = 0.f;

#pragma unroll 4
  for (int c = 0; c < CIN; ++c) {
    const float4 av = *(const float4*)&twt[c][to * 4];
    const float4 pv = *(const float4*)&tin[c][tp * 4];
    const float aa[4] = {av.x, av.y, av.z, av.w};
    const float pp[4] = {pv.x, pv.y, pv.z, pv.w};
#pragma unroll
    for (int i = 0; i < 4; ++i)
#pragma unroll
      for (int j = 0; j < 4; ++j)
        acc[i][j] = __builtin_fmaf(aa[i], pp[j], acc[i][j]);
  }

#pragma unroll
  for (int i = 0; i < 4; ++i) {
    const int o = o0 + to * 4 + i;
    const float Ao = A[o], Bo = Bc[o];
    float4 vv;
    vv.x = fmaxf(__builtin_fmaf(acc[i][0], Ao, Bo), 0.f);
    vv.y = fmaxf(__builtin_fmaf(acc[i][1], Ao, Bo), 0.f);
    vv.z = fmaxf(__builtin_fmaf(acc[i][2], Ao, Bo), 0.f);
    vv.w = fmaxf(__builtin_fmaf(acc[i][3], Ao, Bo), 0.f);
    *(float4*)&outp[((size_t)b * COUT + o) * NN + p0 + tp * 4] = vv;
  }
}

// ---------------- conv5 + BN + ReLU + max-pool: 128o x 128p, 8x8 thread tile ----------------
__global__ __launch_bounds__(256) void k_cgemm5(const float* __restrict__ h4,
                                                const float* __restrict__ wt, // [128][1024]
                                                const float* __restrict__ A,
                                                const float* __restrict__ Bc,
                                                float* __restrict__ pooled) {
  __shared__ float tin[64][128];   // 32 KB (64 c-chunk x 128 points)
  __shared__ float twt[64][128];   // 32 KB (64 c-chunk x 128 outputs)
  const int blk = blockIdx.x;      // 2048 = 8 otiles (fast) x 256 ptiles
  const int ot  = blk & 7;
  const int pt  = blk >> 3;
  const int b   = pt >> 6;
  const int p0  = (pt & 63) * 128;
  const int o0  = ot * 128;
  const int t   = threadIdx.x;
  const int to  = t & 15;          // o-subtile of 8
  const int tp  = t >> 4;          // p-subtile of 8

  float acc[8][8];
#pragma unroll
  for (int i = 0; i < 8; ++i)
#pragma unroll
    for (int j = 0; j < 8; ++j) acc[i][j] = 0.f;

  for (int kc = 0; kc < 128; kc += 64) {
    if (kc) __syncthreads();
    for (int i = t; i < 64 * 32; i += 256) {
      const int c = i >> 5, sg = i & 31;
      *(float4*)&tin[c][sg * 4] =
          *(const float4*)&h4[((size_t)b * 128 + kc + c) * NN + p0 + sg * 4];
      *(float4*)&twt[c][sg * 4] =
          *(const float4*)&wt[(size_t)(kc + c) * 1024 + o0 + sg * 4];
    }
    __syncthreads();
#pragma unroll 2
    for (int c = 0; c < 64; ++c) {
      float w8[8], p8[8];
      *(float4*)&w8[0] = *(const float4*)&twt[c][to * 8];
      *(float4*)&w8[4] = *(const float4*)&twt[c][to * 8 + 4];
      *(float4*)&p8[0] = *(const float4*)&tin[c][tp * 8];
      *(float4*)&p8[4] = *(const float4*)&tin[c][tp * 8 + 4];
#pragma unroll
      for (int i = 0; i < 8; ++i)
#pragma unroll
        for (int j = 0; j < 8; ++j)
          acc[i][j] = __builtin_fmaf(w8[i], p8[j], acc[i][j]);
    }
  }

  float mx[8];
#pragma unroll
  for (int i = 0; i < 8; ++i) {
    const int o = o0 + to * 8 + i;
    const float a = A[o], bo = Bc[o];
    float m = 0.f;   // post-ReLU values are >= 0
#pragma unroll
    for (int j = 0; j < 8; ++j)
      m = fmaxf(m, __builtin_fmaf(acc[i][j], a, bo));
    m = fmaxf(m, 0.f);
    m = fmaxf(m, __shfl_xor(m, 16, 64));
    m = fmaxf(m, __shfl_xor(m, 32, 64));
    mx[i] = m;
  }
  float* s_part = &twt[0][0];      // 512 floats, reused after barrier
  __syncthreads();
  const int lane = t & 63, w = t >> 6;
  if (lane < 16) {
#pragma unroll
    for (int i = 0; i < 8; ++i) s_part[w * 128 + to * 8 + i] = mx[i];
  }
  __syncthreads();
  if (t < 128) {
    const float mm = fmaxf(fmaxf(s_part[t], s_part[128 + t]),
                           fmaxf(s_part[256 + t], s_part[384 + t]));
    atomicMax((int*)pooled + (size_t)b * 1024 + o0 + t, __float_as_int(mm));
  }
}

// ---------------- head: FC1 + BN6 + ReLU ----------------
__global__ __launch_bounds__(256) void k_head1(const float* __restrict__ pooled, const float* __restrict__ lw1,
                        const float* __restrict__ g6, const float* __restrict__ b6,
                        float* __restrict__ sh) {
  const int wv   = threadIdx.x >> 6;
  const int lane = threadIdx.x & 63;
  const int o    = blockIdx.x * 4 + wv;
  const float* __restrict__ wr = lw1 + (size_t)o * 1024;
  float y0 = 0, y1 = 0, y2 = 0, y3 = 0;
  for (int c = lane; c < 1024; c += 64) {
    const float wvv = wr[c];
    y0 = __builtin_fmaf(wvv, pooled[c], y0);
    y1 = __builtin_fmaf(wvv, pooled[1024 + c], y1);
    y2 = __builtin_fmaf(wvv, pooled[2048 + c], y2);
    y3 = __builtin_fmaf(wvv, pooled[3072 + c], y3);
  }
#pragma unroll
  for (int off = 32; off >= 1; off >>= 1) {
    y0 += __shfl_xor(y0, off, 64);
    y1 += __shfl_xor(y1, off, 64);
    y2 += __shfl_xor(y2, off, 64);
    y3 += __shfl_xor(y3, off, 64);
  }
  if (lane == 0) {
    const float mu = 0.25f * (y0 + y1 + y2 + y3);
    const float d0 = y0 - mu, d1 = y1 - mu, d2 = y2 - mu, d3 = y3 - mu;
    const float var = 0.25f * (d0 * d0 + d1 * d1 + d2 * d2 + d3 * d3);
    const float a = g6[o] / sqrtf(var + EPSV);
    const float bc = b6[o];
    sh[o]        = fmaxf(__builtin_fmaf(d0, a, bc), 0.f);
    sh[512 + o]  = fmaxf(__builtin_fmaf(d1, a, bc), 0.f);
    sh[1024 + o] = fmaxf(__builtin_fmaf(d2, a, bc), 0.f);
    sh[1536 + o] = fmaxf(__builtin_fmaf(d3, a, bc), 0.f);
  }
}

// ---------------- head: FC2 ----------------
__global__ void k_head2(const float* __restrict__ sh, const float* __restrict__ lw2,
                        const float* __restrict__ lb2, float* __restrict__ out) {
  const int wv   = threadIdx.x >> 6;
  const int lane = threadIdx.x & 63;
  float s0 = 0, s1 = 0, s2 = 0, s3 = 0;
  for (int c = lane; c < 512; c += 64) {
    const float h = sh[wv * 512 + c];
    s0 = __builtin_fmaf(lw2[c], h, s0);
    s1 = __builtin_fmaf(lw2[512 + c], h, s1);
    s2 = __builtin_fmaf(lw2[1024 + c], h, s2);
    s3 = __builtin_fmaf(lw2[1536 + c], h, s3);
  }
#pragma unroll
  for (int off = 32; off >= 1; off >>= 1) {
    s0 += __shfl_xor(s0, off, 64);
    s1 += __shfl_xor(s1, off, 64);
    s2 += __shfl_xor(s2, off, 64);
    s3 += __shfl_xor(s3, off, 64);
  }
  if (lane == 0) {
    out[wv * 4 + 0] = s0 + lb2[0];
    out[wv * 4 + 1] = s1 + lb2[1];
    out[wv * 4 + 2] = s2 + lb2[2];
    out[wv * 4 + 3] = s3 + lb2[3];
  }
}

extern "C" void kernel_launch(void* const* d_in, const int* in_sizes, int n_in,
                              void* d_out, int out_size, void* d_ws, size_t ws_size,
                              hipStream_t stream) {
  (void)in_sizes; (void)n_in; (void)out_size; (void)ws_size;
  const float* x    = (const float*)d_in[0];
  const void*  lidx = d_in[1];
  const float* w1 = (const float*)d_in[3];
  const float* w2 = (const float*)d_in[4];
  const float* w3 = (const float*)d_in[5];
  const float* w4 = (const float*)d_in[6];
  const float* w5 = (const float*)d_in[7];
  const float* g1 = (const float*)d_in[8],  *b1 = (const float*)d_in[9];
  const float* g2 = (const float*)d_in[10], *b2 = (const float*)d_in[11];
  const float* g3 = (const float*)d_in[12], *b3 = (const float*)d_in[13];
  const float* g4 = (const float*)d_in[14], *b4 = (const float*)d_in[15];
  const float* g5 = (const float*)d_in[16], *b5 = (const float*)d_in[17];
  const float* lw1 = (const float*)d_in[18];
  const float* g6 = (const float*)d_in[19], *b6 = (const float*)d_in[20];
  const float* lw2 = (const float*)d_in[21], *lb2 = (const float*)d_in[22];
  float* out = (float*)d_out;
  float* ws  = (float*)d_ws;

  hipMemsetAsync(ws + OFF_M0, 0, (OFF_ZEND - OFF_M0) * sizeof(float), stream);

  k_prep<<<4, 256, 0, stream>>>((const unsigned int*)lidx, (int*)(ws + OFF_MODE),
                                (int*)(ws + OFF_PCNT), (float4*)(ws + OFF_PL), x);
  k_wtall<<<579, 256, 0, stream>>>(w1, w2, w3, w4, w5, ws + OFF_WT1, ws + OFF_WT2,
                                   ws + OFF_WT3, ws + OFF_WT4, ws + OFF_WT5);
  k_knn<<<512, 512, 0, stream>>>(x, (const float4*)(ws + OFF_PL),
                                 (const int*)(ws + OFF_PCNT), ws + OFF_H0);

  k_stats_small<12><<<128, 256, 0, stream>>>(ws + OFF_H0, ws + OFF_M0, ws + OFF_S0);
  k_solve<12, 64><<<16, 256, 0, stream>>>(w1, g1, b1, ws + OFF_M0, ws + OFF_S0,
                                          ws + OFF_A1, ws + OFF_B1);
  k_cgemm<12, 64><<<512, 256, 0, stream>>>(ws + OFF_H0, ws + OFF_WT1,
                                           ws + OFF_A1, ws + OFF_B1, ws + OFF_H1);

  k_stats<64><<<256, 512, 0, stream>>>(ws + OFF_H1, ws + OFF_P64);
  k_sred<64><<<9, 256, 0, stream>>>(ws + OFF_P64, ws + OFF_M1, ws + OFF_S1);
  k_solve<64, 64><<<16, 256, 0, stream>>>(w2, g2, b2, ws + OFF_M1, ws + OFF_S1,
                                          ws + OFF_A2, ws + OFF_B2);
  k_cgemm<64, 64><<<512, 256, 0, stream>>>(ws + OFF_H1, ws + OFF_WT2,
                                           ws + OFF_A2, ws + OFF_B2, ws + OFF_H2);

  k_stats<64><<<256, 512, 0, stream>>>(ws + OFF_H2, ws + OFF_P64);
  k_sred<64><<<9, 256, 0, stream>>>(ws + OFF_P64, ws + OFF_M2, ws + OFF_S2);
  k_solve<64, 64><<<16, 256, 0, stream>>>(w3, g3, b3, ws + OFF_M2, ws + OFF_S2,
                                          ws + OFF_A3, ws + OFF_B3);
  k_cgemm<64, 64><<<512, 256, 0, stream>>>(ws + OFF_H2, ws + OFF_WT3,
                                           ws + OFF_A3, ws + OFF_B3, ws + OFF_H3);

  k_stats<64><<<256, 512, 0, stream>>>(ws + OFF_H3, ws + OFF_P64);
  k_sred<64><<<9, 256, 0, stream>>>(ws + OFF_P64, ws + OFF_M3, ws + OFF_S3);
  k_solve<64, 128><<<32, 256, 0, stream>>>(w4, g4, b4, ws + OFF_M3, ws + OFF_S3,
                                           ws + OFF_A4, ws + OFF_B4);
  k_cgemm<64, 128><<<1024, 256, 0, stream>>>(ws + OFF_H3, ws + OFF_WT4,
                                             ws + OFF_A4, ws + OFF_B4, ws + OFF_H4);

  k_stats<128><<<256, 512, 0, stream>>>(ws + OFF_H4, ws + OFF_P128);
  k_sred<128><<<35, 256, 0, stream>>>(ws + OFF_P128, ws + OFF_M4, ws + OFF_S4);
  k_solve<128, 1024><<<256, 256, 0, stream>>>(w5, g5, b5, ws + OFF_M4, ws + OFF_S4,
                                              ws + OFF_A5, ws + OFF_B5);
  k_cgemm5<<<2048, 256, 0, stream>>>(ws + OFF_H4, ws + OFF_WT5,
                                     ws + OFF_A5, ws + OFF_B5, ws + OFF_POOL);

  k_head1<<<128, 256, 0, stream>>>(ws + OFF_POOL, lw1, g6, b6, ws + OFF_SH);
  k_head2<<<1, 256, 0, stream>>>(ws + OFF_SH, lw2, lb2, out);
}